// Round 1
// 721.050 us; speedup vs baseline: 1.1184x; 1.1184x over previous
//
#include <hip/hip_runtime.h>
#include <hip/hip_bf16.h>
#include <cstdint>
#include <cstddef>

// Problem constants (B*F tokens)
#define T_TOK 8192
#define DDIM  1024
#define HDIM  2048
#define NEXP  8
#define TOPK  2
#define KAUG  (3 * DDIM)   // split-bf16 router K

typedef short bf16x8 __attribute__((ext_vector_type(8)));
typedef float f32x4  __attribute__((ext_vector_type(4)));

__device__ __forceinline__ unsigned short f2bf(float f) {
  union { float f; unsigned u; } v; v.f = f;
  unsigned r = v.u + 0x7FFFu + ((v.u >> 16) & 1u);
  return (unsigned short)(r >> 16);
}
__device__ __forceinline__ float bf2f(unsigned short h) {
  union { unsigned u; float f; } v; v.u = ((unsigned)h) << 16;
  return v.f;
}
__device__ __forceinline__ float silu_fast(float v) {
  return v / (1.0f + __expf(-v));
}
__device__ __forceinline__ float silu_precise(float v) {
  return v / (1.0f + expf(-v));
}

// async global->LDS, 16B per lane; LDS dest is wave-uniform base + lane*16
__device__ __forceinline__ void gload16(const unsigned short* g, unsigned short* l) {
  __builtin_amdgcn_global_load_lds(
      (const __attribute__((address_space(1))) unsigned int*)g,
      (__attribute__((address_space(3))) unsigned int*)l,
      16, 0, 0);
}

// ---------------- conversion kernels ----------------
// x fp32 -> xaug = [hi | hi | lo] per row (K=3072); hi part doubles as expert A
__global__ void split_x_kernel(const float* __restrict__ in,
                               unsigned short* __restrict__ xaug, int n4) {
  int i = blockIdx.x * blockDim.x + threadIdx.x;
  if (i >= n4) return;
  float4 v = ((const float4*)in)[i];
  int t = i / (DDIM / 4);
  int kc = (i % (DDIM / 4)) * 4;
  float f[4] = {v.x, v.y, v.z, v.w};
  ushort4 hi, lo;
  unsigned short h[4], l[4];
#pragma unroll
  for (int j = 0; j < 4; j++) {
    h[j] = f2bf(f[j]);
    l[j] = f2bf(f[j] - bf2f(h[j]));
  }
  hi.x = h[0]; hi.y = h[1]; hi.z = h[2]; hi.w = h[3];
  lo.x = l[0]; lo.y = l[1]; lo.z = l[2]; lo.w = l[3];
  *(ushort4*)&xaug[(size_t)t * KAUG + kc] = hi;
  *(ushort4*)&xaug[(size_t)t * KAUG + DDIM + kc] = hi;
  *(ushort4*)&xaug[(size_t)t * KAUG + 2 * DDIM + kc] = lo;
}

// rw1 [k][n] fp32 -> waug [n][3072] = [whi | wlo | whi]
__global__ __launch_bounds__(256) void split_w_kernel(
    const float* __restrict__ in, unsigned short* __restrict__ waug) {
  __shared__ float tile[32][33];
  int c0 = blockIdx.x * 32, r0 = blockIdx.y * 32;
  int tx = threadIdx.x & 31, ty = threadIdx.x >> 5;
#pragma unroll
  for (int i = 0; i < 32; i += 8)
    tile[ty + i][tx] = in[(size_t)(r0 + ty + i) * DDIM + (c0 + tx)];
  __syncthreads();
#pragma unroll
  for (int i = 0; i < 32; i += 8) {
    float v = tile[tx][ty + i];          // in[r0+tx][c0+ty+i]
    unsigned short h = f2bf(v);
    unsigned short l = f2bf(v - bf2f(h));
    int n = c0 + ty + i, k = r0 + tx;
    waug[(size_t)n * KAUG + k] = h;
    waug[(size_t)n * KAUG + DDIM + k] = l;
    waug[(size_t)n * KAUG + 2 * DDIM + k] = h;
  }
}

// in: [z][R][C] fp32 -> out: [z][C][R] bf16
__global__ __launch_bounds__(256) void transpose_conv_kernel(
    const float* __restrict__ in, unsigned short* __restrict__ out, int R, int C) {
  __shared__ float tile[32][33];
  const int z = blockIdx.z;
  const float* src = in + (size_t)z * R * C;
  unsigned short* dst = out + (size_t)z * R * C;
  int c0 = blockIdx.x * 32, r0 = blockIdx.y * 32;
  int tx = threadIdx.x & 31, ty = threadIdx.x >> 5;
#pragma unroll
  for (int i = 0; i < 32; i += 8)
    tile[ty + i][tx] = src[(size_t)(r0 + ty + i) * C + (c0 + tx)];
  __syncthreads();
#pragma unroll
  for (int i = 0; i < 32; i += 8)
    dst[(size_t)(c0 + ty + i) * R + (r0 + tx)] = f2bf(tile[tx][ty + i]);
}

__global__ void zero_small_kernel(int* __restrict__ counts, int* __restrict__ cursors) {
  int i = threadIdx.x;
  if (i < NEXP) { counts[i] = 0; cursors[i] = 0; }
}

// ---------------- MFMA GEMM v2: 256xBNT tile, BK=64, 8 waves (2m x 4n) -------
// Double-buffered A and B staged via global_load_lds (16B), LDS XOR-swizzled
// (chunk ^= row&7 on 128B rows) with pre-swizzled global source addresses.
// Per K-tile: {stage A(t+1); read frags ks0; BAR; 32 MFMA; stage B(t+1);
//             read frags ks1; 32 MFMA; vmcnt(0); BAR} — one drain per tile,
// stages issued ~a full tile ahead of their wait.
// EPI=0: router1  -> outF = silu(acc+bias)            (A dense)
// EPI=1: expert1  -> outBf = bf16(silu(acc+bias))     (A gathered by toks)
// EPI=2: expert2  -> outBf = bf16(acc+bias)           (A = packed ehb)
template <int EPI, int BNT>
__global__ __launch_bounds__(512, 2) void gemm_mfma2(
    const unsigned short* __restrict__ Abase,
    const unsigned short* __restrict__ Btbase,  // [z][N][KD] bf16 (pre-transposed)
    const float* __restrict__ bias,             // [z][N]
    float* __restrict__ outF,
    unsigned short* __restrict__ outBf,
    const int* __restrict__ toks,
    const int* __restrict__ offs, const int* __restrict__ cnts,
    int N, int KD, int Astride, int numE, int nTiles, int mCap) {
  constexpr int NI = BNT / 64;     // B frags per wave per k-slice (4 or 2)
  constexpr int RB = BNT / 64;     // B staging rounds (4 or 2)
  constexpr int BB = BNT * 128;    // B buffer bytes (32768 or 16384)
  extern __shared__ char sm[];     // A: 2x32KB at 0; B: 2xBB at 65536

  const int id = blockIdx.x;
  const int e = id % numE;
  const int r = id / numE;
  const int n0 = (r % nTiles) * BNT;
  const int mb = r / nTiles;

  int ne = T_TOK, off = 0;
  if (EPI != 0) { ne = cnts[e]; off = offs[e]; }

  const unsigned short* Bt = Btbase + (size_t)e * N * KD;
  const unsigned short* A = (EPI == 2) ? (Abase + (size_t)off * Astride) : Abase;

  const int tid = threadIdx.x;
  const int lane = tid & 63, wid = tid >> 6;
  const int l16 = lane & 15, quad = lane >> 4;
  const int wm = wid >> 2, wn = wid & 3;     // 2 x 4 waves; wave tile 128 x (BNT/4)

  // staging map: thread tid covers LDS bytes tid*16 of each 8KB round
  const int rStage = tid >> 3;                         // row within 64-row round
  const int cS8 = ((tid & 7) ^ (rStage & 7)) * 8;      // pre-swizzled source chunk
  const int ldsW = wid << 10;                          // wave-uniform LDS base part

  const int NT = KD / 64;
  const int mStride = mCap * 256;

  // frag-read LDS byte offsets (swizzled): chunk ^= (row & 7), row&7 == l16&7
  const int sw = l16 & 7;
  const int cOff0 = (quad ^ sw) << 4;          // k-slice 0
  const int cOff1 = ((quad + 4) ^ sw) << 4;    // k-slice 1
  const int aRowB = (wm * 128 + l16) << 7;     // + mi*(16<<7)
  const int bRowB = (wn * (NI * 16) + l16) << 7;

  const unsigned short* bPtr[RB];
#pragma unroll
  for (int p = 0; p < RB; p++)
    bPtr[p] = Bt + (size_t)(n0 + p * 64 + rStage) * KD + cS8;

  for (int m0 = mb * 256; m0 < ne; m0 += mStride) {
    const unsigned short* aPtr[4];
#pragma unroll
    for (int p = 0; p < 4; p++) {
      int row = m0 + p * 64 + rStage;
      int idx;
      if (EPI == 1) idx = toks[off + min(row, ne - 1)];
      else if (EPI == 2) idx = min(row, ne - 1);
      else idx = row;
      aPtr[p] = A + (size_t)idx * Astride + cS8;
    }

    f32x4 acc[8][NI];
    const f32x4 zf = {0.f, 0.f, 0.f, 0.f};
#pragma unroll
    for (int mi = 0; mi < 8; mi++)
#pragma unroll
      for (int ni = 0; ni < NI; ni++) acc[mi][ni] = zf;

    // prologue: stage K-tile 0 into buffer 0
#pragma unroll
    for (int p = 0; p < 4; p++)
      gload16(aPtr[p], (unsigned short*)(sm + p * 8192 + ldsW));
#pragma unroll
    for (int p = 0; p < RB; p++)
      gload16(bPtr[p], (unsigned short*)(sm + 65536 + p * 8192 + ldsW));
    __builtin_amdgcn_s_waitcnt(0x0F70);  // vmcnt(0)
    __builtin_amdgcn_s_barrier();
    __builtin_amdgcn_sched_barrier(0);

    int cur = 0;
    for (int t = 0; t < NT; ++t) {
      const int nxt = cur ^ 1;
      const bool pf = (t + 1) < NT;
      const int kb = (t + 1) * 64;
      const char* cbA = sm + cur * 32768;
      const char* cbB = sm + 65536 + cur * BB;

      // stage next tile's A early (hides under this tile's MFMAs)
      if (pf) {
#pragma unroll
        for (int p = 0; p < 4; p++)
          gload16(aPtr[p] + kb, (unsigned short*)(sm + nxt * 32768 + p * 8192 + ldsW));
      }
      bf16x8 av[8], bv[NI];
#pragma unroll
      for (int mi = 0; mi < 8; mi++)
        av[mi] = *(const bf16x8*)(cbA + aRowB + (mi << 11) + cOff0);
#pragma unroll
      for (int ni = 0; ni < NI; ni++)
        bv[ni] = *(const bf16x8*)(cbB + bRowB + (ni << 11) + cOff0);
      __builtin_amdgcn_s_barrier();
      __builtin_amdgcn_s_setprio(1);
#pragma unroll
      for (int mi = 0; mi < 8; mi++)
#pragma unroll
        for (int ni = 0; ni < NI; ni++)
          acc[mi][ni] = __builtin_amdgcn_mfma_f32_16x16x32_bf16(
              av[mi], bv[ni], acc[mi][ni], 0, 0, 0);
      __builtin_amdgcn_s_setprio(0);

      // stage next tile's B (L2-warm weights; completes well before the wait)
      if (pf) {
#pragma unroll
        for (int p = 0; p < RB; p++)
          gload16(bPtr[p] + kb,
                  (unsigned short*)(sm + 65536 + nxt * BB + p * 8192 + ldsW));
      }
#pragma unroll
      for (int mi = 0; mi < 8; mi++)
        av[mi] = *(const bf16x8*)(cbA + aRowB + (mi << 11) + cOff1);
#pragma unroll
      for (int ni = 0; ni < NI; ni++)
        bv[ni] = *(const bf16x8*)(cbB + bRowB + (ni << 11) + cOff1);
      __builtin_amdgcn_s_setprio(1);
#pragma unroll
      for (int mi = 0; mi < 8; mi++)
#pragma unroll
        for (int ni = 0; ni < NI; ni++)
          acc[mi][ni] = __builtin_amdgcn_mfma_f32_16x16x32_bf16(
              av[mi], bv[ni], acc[mi][ni], 0, 0, 0);
      __builtin_amdgcn_s_setprio(0);
      __builtin_amdgcn_s_waitcnt(0x0F70);  // vmcnt(0): next tile fully staged
      __builtin_amdgcn_s_barrier();
      __builtin_amdgcn_sched_barrier(0);   // pin: no LDS-read motion across swap
      cur = nxt;
    }

    // epilogue (C/D layout: col = lane&15, row = quad*4 + rr)
    float bv4[NI];
#pragma unroll
    for (int ni = 0; ni < NI; ni++)
      bv4[ni] = bias[(size_t)e * N + n0 + wn * (NI * 16) + ni * 16 + l16];
#pragma unroll
    for (int mi = 0; mi < 8; mi++) {
      const int prow = m0 + wm * 128 + mi * 16 + quad * 4;
#pragma unroll
      for (int rr = 0; rr < 4; rr++) {
        const int p = prow + rr;
        if (EPI != 0 && p >= ne) continue;
#pragma unroll
        for (int ni = 0; ni < NI; ni++) {
          const int col = n0 + wn * (NI * 16) + ni * 16 + l16;
          float v = acc[mi][ni][rr] + bv4[ni];
          if (EPI == 0) {
            outF[(size_t)p * N + col] = silu_precise(v);
          } else if (EPI == 1) {
            outBf[(size_t)(off + p) * N + col] = f2bf(silu_fast(v));
          } else {
            outBf[(size_t)(off + p) * N + col] = f2bf(v);
          }
        }
      }
    }
  }
}

// ---------------- router second layer: logits = rh @ rw2 + rb2 ----------------
__global__ __launch_bounds__(256) void router2_kernel(
    const float* __restrict__ rh, const float* __restrict__ rw2,
    const float* __restrict__ rb2, float* __restrict__ logits) {
  int t = blockIdx.x * 4 + (threadIdx.x >> 6);
  int lane = threadIdx.x & 63;
  const float* row = rh + (size_t)t * DDIM;
  float acc[NEXP];
#pragma unroll
  for (int e = 0; e < NEXP; e++) acc[e] = 0.f;
  for (int k = lane; k < DDIM; k += 64) {
    float v = row[k];
    const float* w = rw2 + (size_t)k * NEXP;
#pragma unroll
    for (int e = 0; e < NEXP; e++) acc[e] += v * w[e];
  }
#pragma unroll
  for (int e = 0; e < NEXP; e++) {
#pragma unroll
    for (int off = 32; off > 0; off >>= 1) acc[e] += __shfl_xor(acc[e], off, 64);
  }
#pragma unroll
  for (int e = 0; e < NEXP; e++)
    if (lane == e) logits[(size_t)t * NEXP + e] = acc[e] + rb2[e];
}

// ---------------- top-2 + softmax + counts ----------------
__global__ void topk_kernel(const float* __restrict__ logits,
                            int* __restrict__ idx2, float* __restrict__ w2arr,
                            int* __restrict__ counts) {
  int t = blockIdx.x * blockDim.x + threadIdx.x;
  if (t >= T_TOK) return;
  float l[NEXP];
#pragma unroll
  for (int e = 0; e < NEXP; e++) l[e] = logits[(size_t)t * NEXP + e];
  int i1 = 0; float v1 = l[0];
#pragma unroll
  for (int e = 1; e < NEXP; e++)
    if (l[e] > v1) { v1 = l[e]; i1 = e; }
  int i2 = -1; float v2 = -3.4e38f;
#pragma unroll
  for (int e = 0; e < NEXP; e++)
    if (e != i1 && l[e] > v2) { v2 = l[e]; i2 = e; }
  float ex = expf(v2 - v1);
  float wa = 1.f / (1.f + ex);
  float wb = ex / (1.f + ex);
  idx2[t * 2] = i1; idx2[t * 2 + 1] = i2;
  w2arr[t * 2] = wa; w2arr[t * 2 + 1] = wb;
  atomicAdd(&counts[i1], 1);
  atomicAdd(&counts[i2], 1);
}

__global__ void prefix_kernel(const int* __restrict__ counts, int* __restrict__ offs) {
  if (threadIdx.x == 0 && blockIdx.x == 0) {
    int s = 0;
    for (int e = 0; e < NEXP; e++) { offs[e] = s; s += counts[e]; }
  }
}

__global__ void scatter_kernel(const int* __restrict__ idx2,
                               const int* __restrict__ offs, int* __restrict__ cursors,
                               int* __restrict__ toks, int* __restrict__ posArr) {
  int t = blockIdx.x * blockDim.x + threadIdx.x;
  if (t >= T_TOK) return;
#pragma unroll
  for (int j = 0; j < TOPK; j++) {
    int e = idx2[t * 2 + j];
    int pos = atomicAdd(&cursors[e], 1);
    int s = offs[e] + pos;
    toks[s] = t;
    posArr[t * 2 + j] = s;
  }
}

// ---------------- final combine: y = x + w0*eo[s0] + w1*eo[s1] ----------------
__global__ __launch_bounds__(256) void combine_kernel(
    const float* __restrict__ x, const unsigned short* __restrict__ eo,
    const int* __restrict__ posArr, const float* __restrict__ w2arr,
    float* __restrict__ y) {
  const int t = blockIdx.x;
  const int d = threadIdx.x * 4;
  const int s0 = posArr[t * 2], s1 = posArr[t * 2 + 1];
  const float w0 = w2arr[t * 2], w1 = w2arr[t * 2 + 1];
  float4 xv = *(const float4*)&x[(size_t)t * DDIM + d];
  ushort4 a = *(const ushort4*)&eo[(size_t)s0 * DDIM + d];
  ushort4 b = *(const ushort4*)&eo[(size_t)s1 * DDIM + d];
  float4 o;
  o.x = xv.x + w0 * bf2f(a.x) + w1 * bf2f(b.x);
  o.y = xv.y + w0 * bf2f(a.y) + w1 * bf2f(b.y);
  o.z = xv.z + w0 * bf2f(a.z) + w1 * bf2f(b.z);
  o.w = xv.w + w0 * bf2f(a.w) + w1 * bf2f(b.w);
  *(float4*)&y[(size_t)t * DDIM + d] = o;
}

// ---------------- launch ----------------
extern "C" void kernel_launch(void* const* d_in, const int* in_sizes, int n_in,
                              void* d_out, int out_size, void* d_ws, size_t ws_size,
                              hipStream_t stream) {
  (void)in_sizes; (void)n_in; (void)out_size; (void)ws_size;
  const float* x   = (const float*)d_in[0];
  const float* rw1 = (const float*)d_in[1];
  const float* rb1 = (const float*)d_in[2];
  const float* rw2 = (const float*)d_in[3];
  const float* rb2 = (const float*)d_in[4];
  const float* ew1 = (const float*)d_in[5];
  const float* eb1 = (const float*)d_in[6];
  const float* ew2 = (const float*)d_in[7];
  const float* eb2 = (const float*)d_in[8];
  float* y = (float*)d_out;

  char* ws = (char*)d_ws;
  size_t o = 0;
  auto alloc = [&](size_t bytes) {
    size_t r = o;
    o += (bytes + 255) & ~(size_t)255;
    return r;
  };
  unsigned short* xaug  = (unsigned short*)(ws + alloc((size_t)T_TOK * KAUG * 2));
  unsigned short* waug  = (unsigned short*)(ws + alloc((size_t)DDIM * KAUG * 2));
  unsigned short* ew1t  = (unsigned short*)(ws + alloc((size_t)NEXP * HDIM * DDIM * 2));
  unsigned short* ew2t  = (unsigned short*)(ws + alloc((size_t)NEXP * DDIM * HDIM * 2));
  float*          rh    = (float*)(ws + alloc((size_t)T_TOK * DDIM * 4));
  float*          logits= (float*)(ws + alloc((size_t)T_TOK * NEXP * 4));
  int*            idx2  = (int*)(ws + alloc((size_t)T_TOK * 2 * 4));
  float*          w2    = (float*)(ws + alloc((size_t)T_TOK * 2 * 4));
  int*            toks  = (int*)(ws + alloc((size_t)T_TOK * TOPK * 4));
  int*            posArr= (int*)(ws + alloc((size_t)T_TOK * TOPK * 4));
  int*            counts= (int*)(ws + alloc(256));
  int*            cursors=(int*)(ws + alloc(256));
  int*            offs  = (int*)(ws + alloc(256));
  unsigned short* ehb   = (unsigned short*)(ws + alloc((size_t)T_TOK * TOPK * HDIM * 2));
  unsigned short* eo    = (unsigned short*)(ws + alloc((size_t)T_TOK * TOPK * DDIM * 2));

  constexpr int LDS_R = 98304;    // BNT=128: A 2x32KB + B 2x16KB
  constexpr int LDS_E = 131072;   // BNT=256: A 2x32KB + B 2x32KB
  static bool s_attr = false;
  if (!s_attr) {
    hipFuncSetAttribute((const void*)gemm_mfma2<0, 128>,
                        hipFuncAttributeMaxDynamicSharedMemorySize, LDS_R);
    hipFuncSetAttribute((const void*)gemm_mfma2<1, 256>,
                        hipFuncAttributeMaxDynamicSharedMemorySize, LDS_E);
    hipFuncSetAttribute((const void*)gemm_mfma2<2, 256>,
                        hipFuncAttributeMaxDynamicSharedMemorySize, LDS_E);
    s_attr = true;
  }

  zero_small_kernel<<<1, 64, 0, stream>>>(counts, cursors);

  const int n4 = T_TOK * DDIM / 4;
  split_x_kernel<<<(n4 + 255) / 256, 256, 0, stream>>>(x, xaug, n4);
  split_w_kernel<<<dim3(DDIM / 32, DDIM / 32), 256, 0, stream>>>(rw1, waug);
  transpose_conv_kernel<<<dim3(HDIM / 32, DDIM / 32, NEXP), 256, 0, stream>>>(ew1, ew1t, DDIM, HDIM);
  transpose_conv_kernel<<<dim3(DDIM / 32, HDIM / 32, NEXP), 256, 0, stream>>>(ew2, ew2t, HDIM, DDIM);

  // router layer 1 (split-bf16, K=3072): rh = silu(x @ rw1 + rb1)
  // 256x128 tiles: numE=1, nTiles=8, mCap=32 -> grid 256 (1 block/CU,
  // XCD = id%8 = n-column -> 768KB B slice per XCD L2)
  gemm_mfma2<0, 128><<<256, 512, LDS_R, stream>>>(
      xaug, waug, rb1, rh, nullptr, nullptr, nullptr, nullptr,
      DDIM, KAUG, KAUG, 1, 8, 32);
  router2_kernel<<<T_TOK / 4, 256, 0, stream>>>(rh, rw2, rb2, logits);
  topk_kernel<<<T_TOK / 256, 256, 0, stream>>>(logits, idx2, w2, counts);
  prefix_kernel<<<1, 64, 0, stream>>>(counts, offs);
  scatter_kernel<<<T_TOK / 256, 256, 0, stream>>>(idx2, offs, cursors, toks, posArr);

  // expert layer 1: ehb = silu(gather(xaug.hi) @ ew1[e] + eb1[e])  (bf16)
  // 256x256 tiles: numE=8 (XCD-aligned), nTiles=8, mCap=16 -> grid 1024
  gemm_mfma2<1, 256><<<8 * 8 * 16, 512, LDS_E, stream>>>(
      xaug, ew1t, eb1, nullptr, ehb, toks, offs, counts,
      HDIM, DDIM, KAUG, NEXP, 8, 16);
  // expert layer 2: eo = ehb @ ew2[e] + eb2[e]  (bf16, packed; weights in combine)
  // numE=8, nTiles=4, mCap=16 -> grid 512
  gemm_mfma2<2, 256><<<8 * 4 * 16, 512, LDS_E, stream>>>(
      ehb, ew2t, eb2, nullptr, eo, nullptr, offs, counts,
      DDIM, HDIM, HDIM, NEXP, 4, 16);
  // y = x + w0*eo[s0] + w1*eo[s1]
  combine_kernel<<<T_TOK, 256, 0, stream>>>(x, eo, posArr, w2, y);
}